// Round 12
// baseline (1691.265 us; speedup 1.0000x reference)
//
#include <hip/hip_runtime.h>
#include <math.h>

// HybridDecoder. B=1024 H=1024 IN=512 OUT=8192 T=15.
// R12: riders right-sized to free chain capacity (256/launch each side);
//      overflow projection work -> one 256^2 8-wave proj256 launch (fp32 out,
//      dual-segment: out1 rows[7680:] + out0 rows[7168:]). Tail removed.
// conv_transpose identity: y[n,o,t] = sum_{2l+k=t} x[n,i,l] * W[o,i,k]

#define HD    1024
#define BATCH 1024
#define IND   512
#define OUTD  8192
#define TSTEPS 15
#define EPSV  1e-5f

typedef unsigned short u16;
typedef __attribute__((ext_vector_type(8))) short bf16x8;
typedef __attribute__((ext_vector_type(8))) unsigned short u16x8;
typedef __attribute__((ext_vector_type(4))) unsigned short u16x4;
typedef __attribute__((ext_vector_type(4))) float f32x4;

__device__ __forceinline__ u16 f2b(float f) {          // fp32 -> bf16 RNE
    union { float f; unsigned u; } x; x.f = f;
    unsigned r = x.u + 0x7fffu + ((x.u >> 16) & 1u);
    return (u16)(r >> 16);
}
__device__ __forceinline__ float b2f(u16 v) {
    union { unsigned u; float f; } x; x.u = ((unsigned)v) << 16; return x.f;
}

typedef __attribute__((address_space(1))) const void gas_t;
typedef __attribute__((address_space(3))) void las_t;
__device__ __forceinline__ void gload_lds16(const u16* g, u16* l) {
    __builtin_amdgcn_global_load_lds((gas_t*)g, (las_t*)l, 16, 0, 0);
}

// ===========================================================================
// m97-structure 128x128 tile (256 thr, 16 KiB LDS via caller pointers)
// ===========================================================================
template<int EPI, bool WF32, bool WB16>
__device__ __forceinline__ void gemm_tile128(
    u16* As, u16* Bs,                    // each 128*32 u16
    int bm, int bn,
    int K1, const u16* A1, int lda1, const u16* B1, int ldb1,
    int K2, const u16* A2, int lda2, const u16* B2, int ldb2,
    const float* bias,
    const float* bng, const float* bnb, const float* bnm, const float* bnv,
    float* Cf, u16* Cb, int ldc)
{
    const int tid  = threadIdx.x;
    const int lane = tid & 63;
    const int w    = tid >> 6;
    const int wr   = w >> 1, wc = w & 1;
    const int r_in = lane >> 2;
    const int c_in = (lane & 3) * 8;

    f32x4 acc[4][4];
#pragma unroll
    for (int m = 0; m < 4; ++m)
#pragma unroll
        for (int n = 0; n < 4; ++n) acc[m][n] = (f32x4){0.f, 0.f, 0.f, 0.f};

#pragma unroll 1
    for (int pair = 0; pair < 2; ++pair) {
        const int K = pair ? K2 : K1;
        if (K == 0) continue;
        const int lda = pair ? lda2 : lda1;
        const int ldb = pair ? ldb2 : ldb1;
        const u16* Ag = (pair ? A2 : A1) + (size_t)bm * lda;
        const u16* Bg = (pair ? B2 : B1) + (size_t)bn * ldb;

        for (int k0 = 0; k0 < K; k0 += 32) {
#pragma unroll
            for (int i = 0; i < 2; ++i) {
                gload_lds16(Ag + (size_t)(i * 64 + w * 16 + r_in) * lda + k0 + c_in,
                            &As[i * 2048 + w * 512]);
                gload_lds16(Bg + (size_t)(i * 64 + w * 16 + r_in) * ldb + k0 + c_in,
                            &Bs[i * 2048 + w * 512]);
            }
            __syncthreads();

            const int fr = lane & 15;
            const int fk = (lane >> 4) * 8;
            bf16x8 av[4], bv[4];
#pragma unroll
            for (int m = 0; m < 4; ++m)
                av[m] = *(const bf16x8*)&As[(wr * 64 + m * 16 + fr) * 32 + fk];
#pragma unroll
            for (int n = 0; n < 4; ++n)
                bv[n] = *(const bf16x8*)&Bs[(wc * 64 + n * 16 + fr) * 32 + fk];
#pragma unroll
            for (int m = 0; m < 4; ++m)
#pragma unroll
                for (int n = 0; n < 4; ++n)
                    acc[m][n] = __builtin_amdgcn_mfma_f32_16x16x32_bf16(
                                    av[m], bv[n], acc[m][n], 0, 0, 0);
            __syncthreads();
        }
    }

    const int col_l = lane & 15;
    const int row_h = (lane >> 4) * 4;
#pragma unroll
    for (int m = 0; m < 4; ++m) {
#pragma unroll
        for (int j = 0; j < 4; ++j) {
            const int row = bm + wr * 64 + m * 16 + row_h + j;
#pragma unroll
            for (int n = 0; n < 4; ++n) {
                const int col = bn + wc * 64 + n * 16 + col_l;
                float v = acc[m][n][j] + bias[col];
                if (EPI == 1) {
                    float e = v > 0.f ? v : expm1f(v);
                    float sc = bng[col] * rsqrtf(bnv[col] + EPSV);
                    v = (e - bnm[col]) * sc + bnb[col];
                }
                if (WF32) Cf[(size_t)row * ldc + col] = v;
                if (WB16) Cb[(size_t)row * ldc + col] = f2b(v);
            }
        }
    }
}

// projection rider: tile g (row-tile g>>6, col-tile g&63), K=1024, fp32 out
__device__ __forceinline__ void proj_rider(u16* sm, int g,
    const u16* A, const u16* B, const float* bias, float* C)
{
    gemm_tile128<0, true, false>(sm, sm + 4096,
        (g >> 6) * 128, (g & 63) * 128,
        HD, A, HD, B, HD, 0, nullptr, 0, nullptr, 0,
        bias, nullptr, nullptr, nullptr, nullptr, C, nullptr, OUTD);
}

// ===========================================================================
// conv stage (dual (l,k) pair), bf16 out
// ===========================================================================
template<int EPI>
__launch_bounds__(256)
__global__ void conv_gemm(int Lin, const u16* X, const u16* W, const float* bias,
                          const float* bng, const float* bnb, const float* bnm, const float* bnv,
                          u16* Y)
{
    __shared__ __align__(16) u16 sm[8192];
    const int t = blockIdx.z;
    int l0 = 0, k0 = 0, l1 = 0, k1 = 0, cnt = 0;
    for (int l = 0; l < Lin; ++l) {
        int k = t - 2 * l;
        if (k >= 0 && k < 3) { if (!cnt) { l0 = l; k0 = k; } else { l1 = l; k1 = k; } ++cnt; }
    }
    const size_t BH = (size_t)BATCH * HD, HH = (size_t)HD * HD;
    gemm_tile128<EPI, false, true>(sm, sm + 4096,
        blockIdx.y * 128, blockIdx.x * 128,
        HD, X + l0 * BH, HD, W + k0 * HH, HD,
        cnt > 1 ? HD : 0, X + l1 * BH, HD, W + k1 * HH, HD,
        bias, bng, bnb, bnm, bnv, nullptr, Y + (size_t)t * BH, HD);
}

// ===========================================================================
// shared 256x256 8-wave GEMM body (1 barrier/K-tile, stage-ahead, swizzled)
// ===========================================================================
struct G256 {
    f32x4 acc[8][4];
};

__device__ __forceinline__ void gemm256_body(u16* smem_, G256& g,
    int bm, int bn, int nk,
    const u16* __restrict__ A, const u16* __restrict__ B, int lda, int ldb)
{
    u16 (*As)[256 * 64] = (u16(*)[256 * 64])smem_;
    u16 (*Bs)[256 * 64] = (u16(*)[256 * 64])(smem_ + 2 * 256 * 64);

    const int tid = threadIdx.x;
    const int w = tid >> 6, l = tid & 63;
    const int wr = w >> 2, wc = w & 3;
    const int srow = l >> 3;
    const int scb  = (l & 7) ^ srow;
    const int fr = l & 15, fcb = l >> 4, swz = l & 7;

    const u16* Ag = A + (size_t)bm * lda;
    const u16* Bg = B + (size_t)bn * ldb;

    auto stage = [&](int b, int kt) {
        const int k0 = kt * 64 + scb * 8;
#pragma unroll
        for (int rr = 0; rr < 4; ++rr)
            gload_lds16(Ag + (size_t)(rr * 64 + w * 8 + srow) * lda + k0,
                        &As[b][(rr * 64 + w * 8) * 64]);
#pragma unroll
        for (int rr = 0; rr < 4; ++rr)
            gload_lds16(Bg + (size_t)(rr * 64 + w * 8 + srow) * ldb + k0,
                        &Bs[b][(rr * 64 + w * 8) * 64]);
    };

#pragma unroll
    for (int m = 0; m < 8; ++m)
#pragma unroll
        for (int n = 0; n < 4; ++n) g.acc[m][n] = (f32x4){0.f, 0.f, 0.f, 0.f};

    stage(0, 0);
    asm volatile("s_waitcnt vmcnt(0)" ::: "memory");
    asm volatile("s_barrier" ::: "memory");

    for (int kt = 0; kt < nk; ++kt) {
        const int c = kt & 1;
        if (kt + 1 < nk) stage(c ^ 1, kt + 1);
#pragma unroll
        for (int ks = 0; ks < 2; ++ks) {
            bf16x8 av[8], bv[4];
#pragma unroll
            for (int m = 0; m < 8; ++m)
                av[m] = *(const bf16x8*)&As[c][
                    (wr * 128 + m * 16 + fr) * 64 + (((ks * 4 + fcb) ^ swz) * 8)];
#pragma unroll
            for (int n = 0; n < 4; ++n)
                bv[n] = *(const bf16x8*)&Bs[c][
                    (wc * 64 + n * 16 + fr) * 64 + (((ks * 4 + fcb) ^ swz) * 8)];
            __builtin_amdgcn_s_setprio(1);
#pragma unroll
            for (int m = 0; m < 8; ++m)
#pragma unroll
                for (int n = 0; n < 4; ++n)
                    g.acc[m][n] = __builtin_amdgcn_mfma_f32_16x16x32_bf16(
                                    av[m], bv[n], g.acc[m][n], 0, 0, 0);
            __builtin_amdgcn_s_setprio(0);
        }
        asm volatile("s_waitcnt vmcnt(0)" ::: "memory");
        asm volatile("s_barrier" ::: "memory");
    }
}

// gdec GEMM: bf16 out, supertile + XCD swizzle (verified R9/R11)
__launch_bounds__(512, 2)
__global__ void gemm256(int nbn, int nk,
    const u16* __restrict__ A, const u16* __restrict__ B,
    const float* __restrict__ bias, u16* __restrict__ Cb,
    int lda, int ldb, int ldc)
{
    const int nwg = gridDim.x;
    const int q = nwg >> 3, r = nwg & 7;
    const int xcd = blockIdx.x & 7, idx = blockIdx.x >> 3;
    const int wg = (xcd < r ? xcd * (q + 1) : r * (q + 1) + (xcd - r) * q) + idx;
    int bm, bn;
    const int nbm = nwg / nbn;
    if ((nbn & 3) == 0 && (nbm & 1) == 0) {
        const int nsc = nbn >> 2;
        const int super = wg >> 3, inner = wg & 7;
        const int sr = super / nsc, sc = super - sr * nsc;
        bm = (sr * 2 + (inner >> 2)) * 256;
        bn = (sc * 4 + (inner & 3)) * 256;
    } else {
        bm = (wg / nbn) * 256;
        bn = (wg % nbn) * 256;
    }

    __shared__ __align__(16) u16 smem[4 * 256 * 64];
    G256 g;
    gemm256_body(smem, g, bm, bn, nk, A, B, lda, ldb);

    const int tid = threadIdx.x;
    const int w = tid >> 6, l = tid & 63;
    const int wr = w >> 2, wc = w & 3;
    const int fr = l & 15;
    float* fsm = (float*)smem;
    const int row_h = (l >> 4) * 4;
#pragma unroll 1
    for (int hh = 0; hh < 2; ++hh) {
        __syncthreads();
        if (wr == hh) {
#pragma unroll
            for (int m = 0; m < 8; ++m)
#pragma unroll
                for (int j = 0; j < 4; ++j) {
                    const int rl = m * 16 + row_h + j;
#pragma unroll
                    for (int n = 0; n < 4; ++n)
                        fsm[rl * 256 + wc * 64 + n * 16 + fr] = g.acc[m][n][j];
                }
        }
        __syncthreads();
#pragma unroll
        for (int it = 0; it < 16; ++it) {
            const int fid = it * 512 + tid;
            const int rl = fid >> 6;
            const int cf = (fid & 63) * 4;
            float4 v = *(const float4*)&fsm[rl * 256 + cf];
            v.x += bias[bn + cf + 0];
            v.y += bias[bn + cf + 1];
            v.z += bias[bn + cf + 2];
            v.w += bias[bn + cf + 3];
            u16x4 o;
            o[0] = f2b(v.x); o[1] = f2b(v.y); o[2] = f2b(v.z); o[3] = f2b(v.w);
            *(u16x4*)&Cb[(size_t)(bm + hh * 128 + rl) * ldc + bn + cf] = o;
        }
    }
}

// final projection remainder: out1 rows[7680:15360) (wg<960) + out0 rows[7168:15360)
__launch_bounds__(512, 2)
__global__ void proj256(
    const u16* __restrict__ Adec, const u16* __restrict__ Bd2o,
    const float* __restrict__ d2ob, float* __restrict__ out1,
    const u16* __restrict__ Ahs, const u16* __restrict__ Bout,
    const float* __restrict__ outb, float* __restrict__ out0)
{
    const int nwg = gridDim.x;             // 1984 = 8*248
    const int q = nwg >> 3, r = nwg & 7;
    const int xcd = blockIdx.x & 7, idx = blockIdx.x >> 3;
    const int wg = (xcd < r ? xcd * (q + 1) : r * (q + 1) + (xcd - r) * q) + idx;

    const u16 *A, *B; const float* bias; float* C;
    int bm, bn;
    if (wg < 960) {                        // out1 segment: nbm=30, nbn=32
        const int super = wg >> 3, inner = wg & 7;
        const int sr = super >> 3, sc = super & 7;     // nsc = 8
        bm = 7680 + (sr * 2 + (inner >> 2)) * 256;
        bn = (sc * 4 + (inner & 3)) * 256;
        A = Adec; B = Bd2o; bias = d2ob; C = out1;
    } else {                               // out0 segment: nbm=32, nbn=32
        const int w2 = wg - 960;
        const int super = w2 >> 3, inner = w2 & 7;
        const int sr = super >> 3, sc = super & 7;
        bm = 7168 + (sr * 2 + (inner >> 2)) * 256;
        bn = (sc * 4 + (inner & 3)) * 256;
        A = Ahs; B = Bout; bias = outb; C = out0;
    }

    __shared__ __align__(16) u16 smem[4 * 256 * 64];
    G256 g;
    gemm256_body(smem, g, bm, bn, HD / 64, A, B, HD, HD);

    const int tid = threadIdx.x;
    const int w = tid >> 6, l = tid & 63;
    const int wr = w >> 2, wc = w & 3;
    const int fr = l & 15;
    float* fsm = (float*)smem;
    const int row_h = (l >> 4) * 4;
#pragma unroll 1
    for (int hh = 0; hh < 2; ++hh) {
        __syncthreads();
        if (wr == hh) {
#pragma unroll
            for (int m = 0; m < 8; ++m)
#pragma unroll
                for (int j = 0; j < 4; ++j) {
                    const int rl = m * 16 + row_h + j;
#pragma unroll
                    for (int n = 0; n < 4; ++n)
                        fsm[rl * 256 + wc * 64 + n * 16 + fr] = g.acc[m][n][j];
                }
        }
        __syncthreads();
#pragma unroll
        for (int it = 0; it < 16; ++it) {
            const int fid = it * 512 + tid;
            const int rl = fid >> 6;
            const int cf = (fid & 63) * 4;
            float4 v = *(const float4*)&fsm[rl * 256 + cf];
            v.x += bias[bn + cf + 0];
            v.y += bias[bn + cf + 1];
            v.z += bias[bn + cf + 2];
            v.w += bias[bn + cf + 3];
            *(float4*)&C[(size_t)(bm + hh * 128 + rl) * OUTD + bn + cf] = v;
        }
    }
}

// ===========================================================================
// GRU step kernels (R9 verified structure) + right-sized riders
// ===========================================================================
#define KTILE(Ag, lda_, Bg, ldb_, k0_, ACC2)                                      \
  {                                                                               \
    const int k0 = (k0_);                                                         \
    gload_lds16((Ag) + (size_t)(tid >> 2) * (lda_) + k0 + (tid & 3) * 8,          \
                &As[tid * 8]);                                                    \
    _Pragma("unroll")                                                             \
    for (int i_ = 0; i_ < 3; ++i_) {                                              \
      const int u_ = tid + i_ * 256;                                              \
      gload_lds16((Bg) + (size_t)((u_ >> 8) * HD + bn + ((u_ & 255) >> 2)) * (ldb_)\
                       + k0 + (u_ & 3) * 8,                                       \
                  &Bs[u_ * 8]);                                                   \
    }                                                                             \
    __syncthreads();                                                              \
    {                                                                             \
      bf16x8 av0 = *(const bf16x8*)&As[(wr * 32 + fr) * 32 + fk];                 \
      bf16x8 av1 = *(const bf16x8*)&As[(wr * 32 + 16 + fr) * 32 + fk];            \
      _Pragma("unroll")                                                           \
      for (int n_ = 0; n_ < 2; ++n_) {                                            \
        const int bo = (wc * 32 + n_ * 16 + fr) * 32 + fk;                        \
        bf16x8 bv = *(const bf16x8*)&Bs[bo];                                      \
        ar[0][n_] = __builtin_amdgcn_mfma_f32_16x16x32_bf16(av0, bv, ar[0][n_], 0, 0, 0); \
        ar[1][n_] = __builtin_amdgcn_mfma_f32_16x16x32_bf16(av1, bv, ar[1][n_], 0, 0, 0); \
        bv = *(const bf16x8*)&Bs[2048 + bo];                                      \
        az[0][n_] = __builtin_amdgcn_mfma_f32_16x16x32_bf16(av0, bv, az[0][n_], 0, 0, 0); \
        az[1][n_] = __builtin_amdgcn_mfma_f32_16x16x32_bf16(av1, bv, az[1][n_], 0, 0, 0); \
        bv = *(const bf16x8*)&Bs[4096 + bo];                                      \
        ACC2[0][n_] = __builtin_amdgcn_mfma_f32_16x16x32_bf16(av0, bv, ACC2[0][n_], 0, 0, 0); \
        ACC2[1][n_] = __builtin_amdgcn_mfma_f32_16x16x32_bf16(av1, bv, ACC2[1][n_], 0, 0, 0); \
      }                                                                           \
    }                                                                             \
    __syncthreads();                                                              \
  }

// gih_cell: bid<256 = chain (gh+gi+cell); bid>=256 = rider on out1 tile t*256+rid
__launch_bounds__(256)
__global__ void gih_cell(int t,
    const u16* __restrict__ inpb,  const u16* __restrict__ wih,
    const u16* __restrict__ hbp,   const u16* __restrict__ whh,
    const u16* __restrict__ gdect, const float* __restrict__ extra0,
    const float* __restrict__ b_hh, const float* __restrict__ hp,
    float* __restrict__ hf, u16* __restrict__ hsbt,
    const u16* __restrict__ dec3b, const u16* __restrict__ d2owb,
    const float* __restrict__ d2ob, float* __restrict__ out1)
{
    __shared__ __align__(16) u16 sm[8192];
    const int bid = blockIdx.x;
    const int tid = threadIdx.x, l = tid & 63, w = tid >> 6;
    const int wr = w >> 1, wc = w & 1;
    const int fr = l & 15, fk = (l >> 4) * 8;

    if (bid >= 256) {   // rider: out1 tiles [t*256, t*256+256)  (rows [0,7680))
        proj_rider(sm, t * 256 + (bid - 256), dec3b, d2owb, d2ob, out1);
        return;
    }

    u16* As = sm;            // 64*32
    u16* Bs = sm + 2048;     // 3*64*32
    const int bm = (bid >> 4) * 64;
    const int bn = (bid & 15) * 64;

    f32x4 ar[2][2], az[2][2], ain[2][2], ahn[2][2];
#pragma unroll
    for (int m = 0; m < 2; ++m)
#pragma unroll
        for (int n = 0; n < 2; ++n) {
            ar[m][n] = (f32x4){0.f, 0.f, 0.f, 0.f};
            az[m][n] = (f32x4){0.f, 0.f, 0.f, 0.f};
            ain[m][n] = (f32x4){0.f, 0.f, 0.f, 0.f};
            ahn[m][n] = (f32x4){0.f, 0.f, 0.f, 0.f};
        }

    const u16* Ah = hbp + (size_t)bm * HD;
    const u16* Ai = inpb + (size_t)bm * IND;
    for (int kt = 0; kt < 32; ++kt)
        KTILE(Ah, HD, whh, HD, kt * 32, ahn);
    if (t > 0)
        for (int kt = 0; kt < 16; ++kt)
            KTILE(Ai, IND, wih, (IND + HD), kt * 32, ain);

    const int rh = (l >> 4) * 4;
#pragma unroll
    for (int m = 0; m < 2; ++m)
#pragma unroll
        for (int n = 0; n < 2; ++n)
#pragma unroll
            for (int j = 0; j < 4; ++j) {
                const int R = bm + wr * 32 + m * 16 + rh + j;
                const int C = bn + wc * 32 + n * 16 + fr;
                const size_t g3 = (size_t)R * (3 * HD);
                float gr  = ar[m][n][j] + b2f(gdect[g3 + C])      + b_hh[C];
                float gz  = az[m][n][j] + b2f(gdect[g3 + HD + C]) + b_hh[HD + C];
                float gin = ain[m][n][j] + b2f(gdect[g3 + 2 * HD + C]);
                float ghn = ahn[m][n][j] + b_hh[2 * HD + C];
                if (extra0) {
                    gr  += extra0[C];
                    gz  += extra0[HD + C];
                    gin += extra0[2 * HD + C];
                }
                const float rg = 1.f / (1.f + expf(-gr));
                const float zg = 1.f / (1.f + expf(-gz));
                const float nn = tanhf(gin + rg * ghn);
                const float h  = (1.f - zg) * nn + zg * hp[(size_t)R * HD + C];
                hf[(size_t)R * HD + C] = h;
                hsbt[(size_t)R * HD + C] = f2b(h);
            }
}

// h2x_k: bid<128 = chain (inp = relu(h@wx^T+xb)); bid>=128 = rider on out0
// tile (t-1)*256 + rid  (rows [(t-1)*512,(t-1)*512+512) -> steps <= (t-1)/2, ready)
__launch_bounds__(256)
__global__ void h2x_k(int t,
    const u16* __restrict__ hbp, const u16* __restrict__ wx,
    const float* __restrict__ xb, u16* __restrict__ inp,
    const u16* __restrict__ hsb, const u16* __restrict__ outwb,
    const float* __restrict__ outb, float* __restrict__ out0)
{
    __shared__ __align__(16) u16 sm[8192];
    const int bid = blockIdx.x;
    const int tid = threadIdx.x, l = tid & 63, w = tid >> 6;
    const int wr = w >> 1, wc = w & 1;
    const int fr = l & 15, fk = (l >> 4) * 8;

    if (bid >= 128) {   // rider: out0 tiles [(t-1)*256, (t-1)*256+256)
        proj_rider(sm, (t - 1) * 256 + (bid - 128), hsb, outwb, outb, out0);
        return;
    }

    u16* As = sm;
    u16* Bs = sm + 2048;
    const int bm = (bid >> 3) * 64;
    const int bn = (bid & 7) * 64;

    f32x4 acc[2][2];
#pragma unroll
    for (int m = 0; m < 2; ++m)
#pragma unroll
        for (int n = 0; n < 2; ++n) acc[m][n] = (f32x4){0.f, 0.f, 0.f, 0.f};
    const u16* Ag = hbp + (size_t)bm * HD;
    const u16* Bg = wx + (size_t)bn * HD;
    for (int kt = 0; kt < 32; ++kt) {
        const int k0 = kt * 32;
        gload_lds16(Ag + (size_t)(tid >> 2) * HD + k0 + (tid & 3) * 8, &As[tid * 8]);
        gload_lds16(Bg + (size_t)(tid >> 2) * HD + k0 + (tid & 3) * 8, &Bs[tid * 8]);
        __syncthreads();
        bf16x8 av0 = *(const bf16x8*)&As[(wr * 32 + fr) * 32 + fk];
        bf16x8 av1 = *(const bf16x8*)&As[(wr * 32 + 16 + fr) * 32 + fk];
#pragma unroll
        for (int n = 0; n < 2; ++n) {
            bf16x8 bv = *(const bf16x8*)&Bs[(wc * 32 + n * 16 + fr) * 32 + fk];
            acc[0][n] = __builtin_amdgcn_mfma_f32_16x16x32_bf16(av0, bv, acc[0][n], 0, 0, 0);
            acc[1][n] = __builtin_amdgcn_mfma_f32_16x16x32_bf16(av1, bv, acc[1][n], 0, 0, 0);
        }
        __syncthreads();
    }
    const int rh = (l >> 4) * 4;
#pragma unroll
    for (int m = 0; m < 2; ++m)
#pragma unroll
        for (int n = 0; n < 2; ++n)
#pragma unroll
            for (int j = 0; j < 4; ++j) {
                const int R = bm + wr * 32 + m * 16 + rh + j;
                const int C = bn + wc * 32 + n * 16 + fr;
                inp[(size_t)R * IND + C] = f2b(fmaxf(acc[m][n][j] + xb[C], 0.f));
            }
}

// ---------------------------------------------------------------------------
__global__ void pack_w3(const float* __restrict__ c1, const float* __restrict__ c2,
                        const float* __restrict__ c3, u16* __restrict__ p1,
                        u16* __restrict__ p2, u16* __restrict__ p3)
{   // (H,H,3) raw [o,i,k] -> bf16 (3,H,H) [k][o][i]
    __shared__ float lds[768];
    const float* cw = blockIdx.y == 0 ? c1 : (blockIdx.y == 1 ? c2 : c3);
    u16* wp = blockIdx.y == 0 ? p1 : (blockIdx.y == 1 ? p2 : p3);
    const int o = blockIdx.x, t = threadIdx.x;
    const float* src = cw + (size_t)o * (HD * 3);
    for (int i0 = 0; i0 < HD; i0 += 256) {
#pragma unroll
        for (int r = 0; r < 3; ++r) lds[t + 256 * r] = src[i0 * 3 + t + 256 * r];
        __syncthreads();
#pragma unroll
        for (int k = 0; k < 3; ++k)
            wp[(size_t)k * HD * HD + (size_t)o * HD + i0 + t] = f2b(lds[t * 3 + k]);
        __syncthreads();
    }
}

__global__ void cvt_all(const float* s0, u16* d0, int n0,
                        const float* s1, u16* d1, int n1,
                        const float* s2, u16* d2, int n2,
                        const float* s3, u16* d3, int n3,
                        const float* s4, u16* d4, int n4,
                        const float* s5, u16* d5, int n5)
{
    const float* s; u16* d; int n;
    switch (blockIdx.y) {
        case 0:  s = s0; d = d0; n = n0; break;
        case 1:  s = s1; d = d1; n = n1; break;
        case 2:  s = s2; d = d2; n = n2; break;
        case 3:  s = s3; d = d3; n = n3; break;
        case 4:  s = s4; d = d4; n = n4; break;
        default: s = s5; d = d5; n = n5; break;
    }
    int i = (blockIdx.x * 256 + threadIdx.x) * 8;
    if (i >= n) return;
    float4 a = *(const float4*)(s + i);
    float4 b = *(const float4*)(s + i + 4);
    u16x8 o;
    o[0] = f2b(a.x); o[1] = f2b(a.y); o[2] = f2b(a.z); o[3] = f2b(a.w);
    o[4] = f2b(b.x); o[5] = f2b(b.y); o[6] = f2b(b.z); o[7] = f2b(b.w);
    *(u16x8*)(d + i) = o;
}

// extra0[j] = 8190 * sum_{k<IND} w_ih[j,k]  (fp32-exact t=0 inp contribution)
__global__ void ext0_k(const float* __restrict__ w_ih, float* __restrict__ e0)
{
    const int j = blockIdx.x, lane = threadIdx.x;   // 64 lanes
    float s = 0.f;
    for (int k = lane; k < IND; k += 64) s += w_ih[(size_t)j * (IND + HD) + k];
    for (int off = 32; off; off >>= 1) s += __shfl_down(s, off);
    if (lane == 0) e0[j] = 8190.f * s;
}

// ---------------------------------------------------------------------------
extern "C" void kernel_launch(void* const* d_in, const int* in_sizes, int n_in,
                              void* d_out, int out_size, void* d_ws, size_t ws_size,
                              hipStream_t stream)
{
    (void)in_sizes; (void)n_in; (void)out_size; (void)ws_size;

    const float* z    = (const float*)d_in[0];
    const float* cw1  = (const float*)d_in[2];
    const float* cb1  = (const float*)d_in[3];
    const float* cw2  = (const float*)d_in[4];
    const float* cb2  = (const float*)d_in[5];
    const float* cw3  = (const float*)d_in[6];
    const float* cb3  = (const float*)d_in[7];
    const float* bn1g = (const float*)d_in[8];
    const float* bn1b = (const float*)d_in[9];
    const float* bn1m = (const float*)d_in[10];
    const float* bn1v = (const float*)d_in[11];
    const float* bn2g = (const float*)d_in[12];
    const float* bn2b = (const float*)d_in[13];
    const float* bn2m = (const float*)d_in[14];
    const float* bn2v = (const float*)d_in[15];
    const float* w_ih = (const float*)d_in[16];
    const float* w_hh = (const float*)d_in[17];
    const float* b_ih = (const float*)d_in[18];
    const float* b_hh = (const float*)d_in[19];
    const float* h2xw = (const float*)d_in[20];
    const float* h2xb = (const float*)d_in[21];
    const float* d2ow = (const float*)d_in[22];
    const float* d2ob = (const float*)d_in[23];
    const float* outw = (const float*)d_in[24];
    const float* outb = (const float*)d_in[25];

    const size_t HH = (size_t)HD * HD, BH = (size_t)BATCH * HD;
    const size_t B3H = (size_t)BATCH * 3 * HD;

    u16* wsb = (u16*)d_ws;
    size_t off = 0;
    auto A16 = [&](size_t n) { u16* p = wsb + off; off += n; return p; };
    u16* wp1   = A16(3 * HH);
    u16* wp2   = A16(3 * HH);
    u16* wp3   = A16(3 * HH);
    u16* wihb  = A16((size_t)3 * HD * (IND + HD));
    u16* whhb  = A16(3 * HH);
    u16* h2xbw = A16((size_t)IND * HD);
    u16* outwb = A16((size_t)OUTD * HD);
    u16* d2owb = A16((size_t)OUTD * HD);
    u16* zb    = A16(BH);
    u16* decab = A16(3 * BH);
    u16* decbb = A16(7 * BH);
    u16* dec3b = A16(15 * BH);
    u16* hsb   = A16(15 * BH);
    u16* inpb  = A16((size_t)BATCH * IND);
    u16* gdecb = A16((size_t)TSTEPS * B3H);     // bf16 gdec (~94 MB)
    float* wsf = (float*)(wsb + ((off + 1) & ~(size_t)1));
    size_t foff = 0;
    auto A32 = [&](size_t n) { float* p = wsf + foff; foff += n; return p; };
    float* h0f   = A32(BH);
    float* h1f   = A32(BH);
    float* extra0= A32(3 * HD);

    pack_w3<<<dim3(HD, 3), 256, 0, stream>>>(cw1, cw2, cw3, wp1, wp2, wp3);
    cvt_all<<<dim3(4096, 6), 256, 0, stream>>>(
        z, zb, (int)BH,
        w_ih, wihb, 3 * HD * (IND + HD),
        w_hh, whhb, (int)(3 * HH),
        h2xw, h2xbw, IND * HD,
        outw, outwb, OUTD * HD,
        d2ow, d2owb, OUTD * HD);
    ext0_k<<<3 * HD, 64, 0, stream>>>(w_ih, extra0);

    conv_gemm<1><<<dim3(8, 8, 3), 256, 0, stream>>>(1, zb, wp1, cb1,
        bn1g, bn1b, bn1m, bn1v, decab);
    conv_gemm<1><<<dim3(8, 8, 7), 256, 0, stream>>>(3, decab, wp2, cb2,
        bn2g, bn2b, bn2m, bn2v, decbb);
    conv_gemm<0><<<dim3(8, 8, 15), 256, 0, stream>>>(7, decbb, wp3, cb3,
        nullptr, nullptr, nullptr, nullptr, dec3b);

    // gdec[t] = dec_tbh @ w_ih[:,512:]^T + b_ih  for all t (parallel, bf16 out)
    gemm256<<<dim3((TSTEPS * BATCH / 256) * (3 * HD / 256)), 512, 0, stream>>>(
        3 * HD / 256, HD / 64,
        dec3b, wihb + IND, b_ih, gdecb, HD, IND + HD, 3 * HD);

    // ---- GRU chain with right-sized riders ----
    float* out0 = (float*)d_out;
    float* out1 = out0 + (size_t)TSTEPS * BATCH * OUTD;
    for (int t = 0; t < TSTEPS; ++t) {
        const u16* hbp   = t ? hsb + (size_t)(t - 1) * BH : zb;
        const float* hpf = (t == 0) ? z : (((t - 1) & 1) ? h1f : h0f);
        float* hwf = (t & 1) ? h1f : h0f;
        if (t > 0)   // 128 chain blocks + 256 out0 riders
            h2x_k<<<384, 256, 0, stream>>>(t, hbp, h2xbw, h2xb, inpb,
                hsb, outwb, outb, out0);
        // 256 chain blocks + 256 out1 riders
        gih_cell<<<512, 256, 0, stream>>>(t,
            inpb, wihb, hbp, whhb, gdecb + (size_t)t * B3H,
            t ? nullptr : extra0, b_hh, hpf, hwf, hsb + (size_t)t * BH,
            dec3b, d2owb, d2ob, out1);
    }
    // final: out1 rows [7680,15360) + out0 rows [7168,15360)
    proj256<<<1984, 512, 0, stream>>>(dec3b, d2owb, d2ob, out1,
                                      hsb, outwb, outb, out0);
}

// Round 13
// 1484.549 us; speedup vs baseline: 1.1392x; 1.1392x over previous
//
#include <hip/hip_runtime.h>
#include <math.h>

// HybridDecoder. B=1024 H=1024 IN=512 OUT=8192 T=15.
// R13 = R11 (best, 1514us) + gdec folded into the chain shadow:
//   gih(t) riders compute gdec[t+2] tiles (192) + out1 tiles (512);
//   gdec[0..1] from a small head launch. The 720-block gdec launch is gone.
// conv_transpose identity: y[n,o,t] = sum_{2l+k=t} x[n,i,l] * W[o,i,k]

#define HD    1024
#define BATCH 1024
#define IND   512
#define OUTD  8192
#define TSTEPS 15
#define EPSV  1e-5f

typedef unsigned short u16;
typedef __attribute__((ext_vector_type(8))) short bf16x8;
typedef __attribute__((ext_vector_type(8))) unsigned short u16x8;
typedef __attribute__((ext_vector_type(4))) unsigned short u16x4;
typedef __attribute__((ext_vector_type(4))) float f32x4;

__device__ __forceinline__ u16 f2b(float f) {          // fp32 -> bf16 RNE
    union { float f; unsigned u; } x; x.f = f;
    unsigned r = x.u + 0x7fffu + ((x.u >> 16) & 1u);
    return (u16)(r >> 16);
}
__device__ __forceinline__ float b2f(u16 v) {
    union { unsigned u; float f; } x; x.u = ((unsigned)v) << 16; return x.f;
}

typedef __attribute__((address_space(1))) const void gas_t;
typedef __attribute__((address_space(3))) void las_t;
__device__ __forceinline__ void gload_lds16(const u16* g, u16* l) {
    __builtin_amdgcn_global_load_lds((gas_t*)g, (las_t*)l, 16, 0, 0);
}

// ===========================================================================
// m97-structure 128x128 tile (256 thr, 16 KiB LDS via caller pointers)
// ===========================================================================
template<int EPI, bool WF32, bool WB16>
__device__ __forceinline__ void gemm_tile128(
    u16* As, u16* Bs,                    // each 128*32 u16
    int bm, int bn,
    int K1, const u16* A1, int lda1, const u16* B1, int ldb1,
    int K2, const u16* A2, int lda2, const u16* B2, int ldb2,
    const float* bias,
    const float* bng, const float* bnb, const float* bnm, const float* bnv,
    float* Cf, u16* Cb, int ldc)
{
    const int tid  = threadIdx.x;
    const int lane = tid & 63;
    const int w    = tid >> 6;
    const int wr   = w >> 1, wc = w & 1;
    const int r_in = lane >> 2;
    const int c_in = (lane & 3) * 8;

    f32x4 acc[4][4];
#pragma unroll
    for (int m = 0; m < 4; ++m)
#pragma unroll
        for (int n = 0; n < 4; ++n) acc[m][n] = (f32x4){0.f, 0.f, 0.f, 0.f};

#pragma unroll 1
    for (int pair = 0; pair < 2; ++pair) {
        const int K = pair ? K2 : K1;
        if (K == 0) continue;
        const int lda = pair ? lda2 : lda1;
        const int ldb = pair ? ldb2 : ldb1;
        const u16* Ag = (pair ? A2 : A1) + (size_t)bm * lda;
        const u16* Bg = (pair ? B2 : B1) + (size_t)bn * ldb;

        for (int k0 = 0; k0 < K; k0 += 32) {
#pragma unroll
            for (int i = 0; i < 2; ++i) {
                gload_lds16(Ag + (size_t)(i * 64 + w * 16 + r_in) * lda + k0 + c_in,
                            &As[i * 2048 + w * 512]);
                gload_lds16(Bg + (size_t)(i * 64 + w * 16 + r_in) * ldb + k0 + c_in,
                            &Bs[i * 2048 + w * 512]);
            }
            __syncthreads();

            const int fr = lane & 15;
            const int fk = (lane >> 4) * 8;
            bf16x8 av[4], bv[4];
#pragma unroll
            for (int m = 0; m < 4; ++m)
                av[m] = *(const bf16x8*)&As[(wr * 64 + m * 16 + fr) * 32 + fk];
#pragma unroll
            for (int n = 0; n < 4; ++n)
                bv[n] = *(const bf16x8*)&Bs[(wc * 64 + n * 16 + fr) * 32 + fk];
#pragma unroll
            for (int m = 0; m < 4; ++m)
#pragma unroll
                for (int n = 0; n < 4; ++n)
                    acc[m][n] = __builtin_amdgcn_mfma_f32_16x16x32_bf16(
                                    av[m], bv[n], acc[m][n], 0, 0, 0);
            __syncthreads();
        }
    }

    const int col_l = lane & 15;
    const int row_h = (lane >> 4) * 4;
#pragma unroll
    for (int m = 0; m < 4; ++m) {
#pragma unroll
        for (int j = 0; j < 4; ++j) {
            const int row = bm + wr * 64 + m * 16 + row_h + j;
#pragma unroll
            for (int n = 0; n < 4; ++n) {
                const int col = bn + wc * 64 + n * 16 + col_l;
                float v = acc[m][n][j] + bias[col];
                if (EPI == 1) {
                    float e = v > 0.f ? v : expm1f(v);
                    float sc = bng[col] * rsqrtf(bnv[col] + EPSV);
                    v = (e - bnm[col]) * sc + bnb[col];
                }
                if (WF32) Cf[(size_t)row * ldc + col] = v;
                if (WB16) Cb[(size_t)row * ldc + col] = f2b(v);
            }
        }
    }
}

// projection rider: tile g (row-tile g>>6, col-tile g&63), K=1024, fp32 out
__device__ __forceinline__ void proj_rider(u16* sm, int g,
    const u16* A, const u16* B, const float* bias, float* C)
{
    gemm_tile128<0, true, false>(sm, sm + 4096,
        (g >> 6) * 128, (g & 63) * 128,
        HD, A, HD, B, HD, 0, nullptr, 0, nullptr, 0,
        bias, nullptr, nullptr, nullptr, nullptr, C, nullptr, OUTD);
}

// gdec rider: gdec[t] tile g (8x24 tiles of 128^2), bf16 out into gdecb
__device__ __forceinline__ void gdec_rider(u16* sm, int t, int g,
    const u16* dec3b, const u16* wihb, const float* b_ih, u16* gdecb)
{
    const int row = g / 24, col = g - row * 24;
    gemm_tile128<0, false, true>(sm, sm + 4096,
        row * 128, col * 128,
        HD, dec3b + (size_t)t * BATCH * HD, HD, wihb + IND, IND + HD,
        0, nullptr, 0, nullptr, 0,
        b_ih, nullptr, nullptr, nullptr, nullptr,
        nullptr, gdecb + (size_t)t * BATCH * 3 * HD, 3 * HD);
}

// head launch: gdec[0] (bid<192) and gdec[1] (bid>=192)
__launch_bounds__(256)
__global__ void gdec_head(const u16* __restrict__ dec3b, const u16* __restrict__ wihb,
                          const float* __restrict__ b_ih, u16* __restrict__ gdecb)
{
    __shared__ __align__(16) u16 sm[8192];
    const int bid = blockIdx.x;
    if (bid < 192) gdec_rider(sm, 0, bid, dec3b, wihb, b_ih, gdecb);
    else           gdec_rider(sm, 1, bid - 192, dec3b, wihb, b_ih, gdecb);
}

// ===========================================================================
// conv stage (dual (l,k) pair), bf16 out
// ===========================================================================
template<int EPI>
__launch_bounds__(256)
__global__ void conv_gemm(int Lin, const u16* X, const u16* W, const float* bias,
                          const float* bng, const float* bnb, const float* bnm, const float* bnv,
                          u16* Y)
{
    __shared__ __align__(16) u16 sm[8192];
    const int t = blockIdx.z;
    int l0 = 0, k0 = 0, l1 = 0, k1 = 0, cnt = 0;
    for (int l = 0; l < Lin; ++l) {
        int k = t - 2 * l;
        if (k >= 0 && k < 3) { if (!cnt) { l0 = l; k0 = k; } else { l1 = l; k1 = k; } ++cnt; }
    }
    const size_t BH = (size_t)BATCH * HD, HH = (size_t)HD * HD;
    gemm_tile128<EPI, false, true>(sm, sm + 4096,
        blockIdx.y * 128, blockIdx.x * 128,
        HD, X + l0 * BH, HD, W + k0 * HH, HD,
        cnt > 1 ? HD : 0, X + l1 * BH, HD, W + k1 * HH, HD,
        bias, bng, bnb, bnm, bnv, nullptr, Y + (size_t)t * BH, HD);
}

// ===========================================================================
// GRU step kernels (R9/R11 verified structure) + riders
// ===========================================================================
#define KTILE(Ag, lda_, Bg, ldb_, k0_, ACC2)                                      \
  {                                                                               \
    const int k0 = (k0_);                                                         \
    gload_lds16((Ag) + (size_t)(tid >> 2) * (lda_) + k0 + (tid & 3) * 8,          \
                &As[tid * 8]);                                                    \
    _Pragma("unroll")                                                             \
    for (int i_ = 0; i_ < 3; ++i_) {                                              \
      const int u_ = tid + i_ * 256;                                              \
      gload_lds16((Bg) + (size_t)((u_ >> 8) * HD + bn + ((u_ & 255) >> 2)) * (ldb_)\
                       + k0 + (u_ & 3) * 8,                                       \
                  &Bs[u_ * 8]);                                                   \
    }                                                                             \
    __syncthreads();                                                              \
    {                                                                             \
      bf16x8 av0 = *(const bf16x8*)&As[(wr * 32 + fr) * 32 + fk];                 \
      bf16x8 av1 = *(const bf16x8*)&As[(wr * 32 + 16 + fr) * 32 + fk];            \
      _Pragma("unroll")                                                           \
      for (int n_ = 0; n_ < 2; ++n_) {                                            \
        const int bo = (wc * 32 + n_ * 16 + fr) * 32 + fk;                        \
        bf16x8 bv = *(const bf16x8*)&Bs[bo];                                      \
        ar[0][n_] = __builtin_amdgcn_mfma_f32_16x16x32_bf16(av0, bv, ar[0][n_], 0, 0, 0); \
        ar[1][n_] = __builtin_amdgcn_mfma_f32_16x16x32_bf16(av1, bv, ar[1][n_], 0, 0, 0); \
        bv = *(const bf16x8*)&Bs[2048 + bo];                                      \
        az[0][n_] = __builtin_amdgcn_mfma_f32_16x16x32_bf16(av0, bv, az[0][n_], 0, 0, 0); \
        az[1][n_] = __builtin_amdgcn_mfma_f32_16x16x32_bf16(av1, bv, az[1][n_], 0, 0, 0); \
        bv = *(const bf16x8*)&Bs[4096 + bo];                                      \
        ACC2[0][n_] = __builtin_amdgcn_mfma_f32_16x16x32_bf16(av0, bv, ACC2[0][n_], 0, 0, 0); \
        ACC2[1][n_] = __builtin_amdgcn_mfma_f32_16x16x32_bf16(av1, bv, ACC2[1][n_], 0, 0, 0); \
      }                                                                           \
    }                                                                             \
    __syncthreads();                                                              \
  }

// gih_cell: bid<256 = chain (gh+gi+cell);
//   t<=12: bid in [256,448) = gdec[t+2] rider; [448,960) = out1 rider t*512+rid
//   t>12 : bid in [256,768) = out1 rider t*512+rid
__launch_bounds__(256)
__global__ void gih_cell(int t,
    const u16* __restrict__ inpb,  const u16* __restrict__ wih,
    const u16* __restrict__ hbp,   const u16* __restrict__ whh,
    const u16* __restrict__ gdecb, const float* __restrict__ extra0,
    const float* __restrict__ b_hh, const float* __restrict__ hp,
    float* __restrict__ hf, u16* __restrict__ hsbt,
    const u16* __restrict__ dec3b, const u16* __restrict__ d2owb,
    const float* __restrict__ d2ob, float* __restrict__ out1,
    const float* __restrict__ b_ih)
{
    __shared__ __align__(16) u16 sm[8192];
    const int bid = blockIdx.x;
    const int tid = threadIdx.x, l = tid & 63, w = tid >> 6;
    const int wr = w >> 1, wc = w & 1;
    const int fr = l & 15, fk = (l >> 4) * 8;

    if (bid >= 256) {
        int rid = bid - 256;
        if (t <= 12) {
            if (rid < 192) {   // gdec[t+2] rider (consumed 2 launches later)
                gdec_rider(sm, t + 2, rid, dec3b, wih, b_ih, (u16*)gdecb);
                return;
            }
            rid -= 192;
        }
        proj_rider(sm, t * 512 + rid, dec3b, d2owb, d2ob, out1);   // out1
        return;
    }

    u16* As = sm;            // 64*32
    u16* Bs = sm + 2048;     // 3*64*32
    const int bm = (bid >> 4) * 64;
    const int bn = (bid & 15) * 64;

    f32x4 ar[2][2], az[2][2], ain[2][2], ahn[2][2];
#pragma unroll
    for (int m = 0; m < 2; ++m)
#pragma unroll
        for (int n = 0; n < 2; ++n) {
            ar[m][n] = (f32x4){0.f, 0.f, 0.f, 0.f};
            az[m][n] = (f32x4){0.f, 0.f, 0.f, 0.f};
            ain[m][n] = (f32x4){0.f, 0.f, 0.f, 0.f};
            ahn[m][n] = (f32x4){0.f, 0.f, 0.f, 0.f};
        }

    const u16* Ah = hbp + (size_t)bm * HD;
    const u16* Ai = inpb + (size_t)bm * IND;
    for (int kt = 0; kt < 32; ++kt)
        KTILE(Ah, HD, whh, HD, kt * 32, ahn);
    if (t > 0)
        for (int kt = 0; kt < 16; ++kt)
            KTILE(Ai, IND, wih, (IND + HD), kt * 32, ain);

    const u16* gdect = gdecb + (size_t)t * BATCH * 3 * HD;
    const int rh = (l >> 4) * 4;
#pragma unroll
    for (int m = 0; m < 2; ++m)
#pragma unroll
        for (int n = 0; n < 2; ++n)
#pragma unroll
            for (int j = 0; j < 4; ++j) {
                const int R = bm + wr * 32 + m * 16 + rh + j;
                const int C = bn + wc * 32 + n * 16 + fr;
                const size_t g3 = (size_t)R * (3 * HD);
                float gr  = ar[m][n][j] + b2f(gdect[g3 + C])      + b_hh[C];
                float gz  = az[m][n][j] + b2f(gdect[g3 + HD + C]) + b_hh[HD + C];
                float gin = ain[m][n][j] + b2f(gdect[g3 + 2 * HD + C]);
                float ghn = ahn[m][n][j] + b_hh[2 * HD + C];
                if (extra0) {
                    gr  += extra0[C];
                    gz  += extra0[HD + C];
                    gin += extra0[2 * HD + C];
                }
                const float rg = 1.f / (1.f + expf(-gr));
                const float zg = 1.f / (1.f + expf(-gz));
                const float nn = tanhf(gin + rg * ghn);
                const float h  = (1.f - zg) * nn + zg * hp[(size_t)R * HD + C];
                hf[(size_t)R * HD + C] = h;
                hsbt[(size_t)R * HD + C] = f2b(h);
            }
}

// h2x_k: bid<128 = chain (inp = relu(h@wx^T+xb)); bid>=128 = rider on out0
// tile (t-1)*512 + rid  (h_{t-1} rows of out0; hsb is t-major so A base = hsb)
__launch_bounds__(256)
__global__ void h2x_k(int t,
    const u16* __restrict__ hbp, const u16* __restrict__ wx,
    const float* __restrict__ xb, u16* __restrict__ inp,
    const u16* __restrict__ hsb, const u16* __restrict__ outwb,
    const float* __restrict__ outb, float* __restrict__ out0)
{
    __shared__ __align__(16) u16 sm[8192];
    const int bid = blockIdx.x;
    const int tid = threadIdx.x, l = tid & 63, w = tid >> 6;
    const int wr = w >> 1, wc = w & 1;
    const int fr = l & 15, fk = (l >> 4) * 8;

    if (bid >= 128) {   // rider: out0 tiles for step t-1
        proj_rider(sm, (t - 1) * 512 + (bid - 128), hsb, outwb, outb, out0);
        return;
    }

    u16* As = sm;
    u16* Bs = sm + 2048;
    const int bm = (bid >> 3) * 64;
    const int bn = (bid & 7) * 64;

    f32x4 acc[2][2];
#pragma unroll
    for (int m = 0; m < 2; ++m)
#pragma unroll
        for (int n = 0; n < 2; ++n) acc[m][n] = (f32x4){0.f, 0.f, 0.f, 0.f};
    const u16* Ag = hbp + (size_t)bm * HD;
    const u16* Bg = wx + (size_t)bn * HD;
    for (int kt = 0; kt < 32; ++kt) {
        const int k0 = kt * 32;
        gload_lds16(Ag + (size_t)(tid >> 2) * HD + k0 + (tid & 3) * 8, &As[tid * 8]);
        gload_lds16(Bg + (size_t)(tid >> 2) * HD + k0 + (tid & 3) * 8, &Bs[tid * 8]);
        __syncthreads();
        bf16x8 av0 = *(const bf16x8*)&As[(wr * 32 + fr) * 32 + fk];
        bf16x8 av1 = *(const bf16x8*)&As[(wr * 32 + 16 + fr) * 32 + fk];
#pragma unroll
        for (int n = 0; n < 2; ++n) {
            bf16x8 bv = *(const bf16x8*)&Bs[(wc * 32 + n * 16 + fr) * 32 + fk];
            acc[0][n] = __builtin_amdgcn_mfma_f32_16x16x32_bf16(av0, bv, acc[0][n], 0, 0, 0);
            acc[1][n] = __builtin_amdgcn_mfma_f32_16x16x32_bf16(av1, bv, acc[1][n], 0, 0, 0);
        }
        __syncthreads();
    }
    const int rh = (l >> 4) * 4;
#pragma unroll
    for (int m = 0; m < 2; ++m)
#pragma unroll
        for (int n = 0; n < 2; ++n)
#pragma unroll
            for (int j = 0; j < 4; ++j) {
                const int R = bm + wr * 32 + m * 16 + rh + j;
                const int C = bn + wc * 32 + n * 16 + fr;
                inp[(size_t)R * IND + C] = f2b(fmaxf(acc[m][n][j] + xb[C], 0.f));
            }
}

// tail: out0 tiles for step 14 (512 blocks)
__launch_bounds__(256)
__global__ void proj_k(int g0, const u16* __restrict__ A, const u16* __restrict__ B,
                       const float* __restrict__ bias, float* __restrict__ C)
{
    __shared__ __align__(16) u16 sm[8192];
    proj_rider(sm, g0 + blockIdx.x, A, B, bias, C);
}

// ---------------------------------------------------------------------------
__global__ void pack_w3(const float* __restrict__ c1, const float* __restrict__ c2,
                        const float* __restrict__ c3, u16* __restrict__ p1,
                        u16* __restrict__ p2, u16* __restrict__ p3)
{   // (H,H,3) raw [o,i,k] -> bf16 (3,H,H) [k][o][i]
    __shared__ float lds[768];
    const float* cw = blockIdx.y == 0 ? c1 : (blockIdx.y == 1 ? c2 : c3);
    u16* wp = blockIdx.y == 0 ? p1 : (blockIdx.y == 1 ? p2 : p3);
    const int o = blockIdx.x, t = threadIdx.x;
    const float* src = cw + (size_t)o * (HD * 3);
    for (int i0 = 0; i0 < HD; i0 += 256) {
#pragma unroll
        for (int r = 0; r < 3; ++r) lds[t + 256 * r] = src[i0 * 3 + t + 256 * r];
        __syncthreads();
#pragma unroll
        for (int k = 0; k < 3; ++k)
            wp[(size_t)k * HD * HD + (size_t)o * HD + i0 + t] = f2b(lds[t * 3 + k]);
        __syncthreads();
    }
}

__global__ void cvt_all(const float* s0, u16* d0, int n0,
                        const float* s1, u16* d1, int n1,
                        const float* s2, u16* d2, int n2,
                        const float* s3, u16* d3, int n3,
                        const float* s4, u16* d4, int n4,
                        const float* s5, u16* d5, int n5)
{
    const float* s; u16* d; int n;
    switch (blockIdx.y) {
        case 0:  s = s0; d = d0; n = n0; break;
        case 1:  s = s1; d = d1; n = n1; break;
        case 2:  s = s2; d = d2; n = n2; break;
        case 3:  s = s3; d = d3; n = n3; break;
        case 4:  s = s4; d = d4; n = n4; break;
        default: s = s5; d = d5; n = n5; break;
    }
    int i = (blockIdx.x * 256 + threadIdx.x) * 8;
    if (i >= n) return;
    float4 a = *(const float4*)(s + i);
    float4 b = *(const float4*)(s + i + 4);
    u16x8 o;
    o[0] = f2b(a.x); o[1] = f2b(a.y); o[2] = f2b(a.z); o[3] = f2b(a.w);
    o[4] = f2b(b.x); o[5] = f2b(b.y); o[6] = f2b(b.z); o[7] = f2b(b.w);
    *(u16x8*)(d + i) = o;
}

// extra0[j] = 8190 * sum_{k<IND} w_ih[j,k]  (fp32-exact t=0 inp contribution)
__global__ void ext0_k(const float* __restrict__ w_ih, float* __restrict__ e0)
{
    const int j = blockIdx.x, lane = threadIdx.x;   // 64 lanes
    float s = 0.f;
    for (int k = lane; k < IND; k += 64) s += w_ih[(size_t)j * (IND + HD) + k];
    for (int off = 32; off; off >>= 1) s += __shfl_down(s, off);
    if (lane == 0) e0[j] = 8190.f * s;
}

// ---------------------------------------------------------------------------
extern "C" void kernel_launch(void* const* d_in, const int* in_sizes, int n_in,
                              void* d_out, int out_size, void* d_ws, size_t ws_size,
                              hipStream_t stream)
{
    (void)in_sizes; (void)n_in; (void)out_size; (void)ws_size;

    const float* z    = (const float*)d_in[0];
    const float* cw1  = (const float*)d_in[2];
    const float* cb1  = (const float*)d_in[3];
    const float* cw2  = (const float*)d_in[4];
    const float* cb2  = (const float*)d_in[5];
    const float* cw3  = (const float*)d_in[6];
    const float* cb3  = (const float*)d_in[7];
    const float* bn1g = (const float*)d_in[8];
    const float* bn1b = (const float*)d_in[9];
    const float* bn1m = (const float*)d_in[10];
    const float* bn1v = (const float*)d_in[11];
    const float* bn2g = (const float*)d_in[12];
    const float* bn2b = (const float*)d_in[13];
    const float* bn2m = (const float*)d_in[14];
    const float* bn2v = (const float*)d_in[15];
    const float* w_ih = (const float*)d_in[16];
    const float* w_hh = (const float*)d_in[17];
    const float* b_ih = (const float*)d_in[18];
    const float* b_hh = (const float*)d_in[19];
    const float* h2xw = (const float*)d_in[20];
    const float* h2xb = (const float*)d_in[21];
    const float* d2ow = (const float*)d_in[22];
    const float* d2ob = (const float*)d_in[23];
    const float* outw = (const float*)d_in[24];
    const float* outb = (const float*)d_in[25];

    const size_t HH = (size_t)HD * HD, BH = (size_t)BATCH * HD;
    const size_t B3H = (size_t)BATCH * 3 * HD;

    u16* wsb = (u16*)d_ws;
    size_t off = 0;
    auto A16 = [&](size_t n) { u16* p = wsb + off; off += n; return p; };
    u16* wp1   = A16(3 * HH);
    u16* wp2   = A16(3 * HH);
    u16* wp3   = A16(3 * HH);
    u16* wihb  = A16((size_t)3 * HD * (IND + HD));
    u16* whhb  = A16(3 * HH);
    u16* h2xbw = A16((size_t)IND * HD);
    u16* outwb = A16((size_t)OUTD * HD);
    u16* d2owb = A16((size_t)OUTD * HD);
    u16* zb    = A16(BH);
    u16* decab = A16(3 * BH);
    u16* decbb = A16(7 * BH);
    u16* dec3b = A16(15 * BH);
    u16* hsb   = A16(15 * BH);
    u16* inpb  = A16((size_t)BATCH * IND);
    u16* gdecb = A16((size_t)TSTEPS * B3H);     // bf16 gdec (~94 MB)
    float* wsf = (float*)(wsb + ((off + 1) & ~(size_t)1));
    size_t foff = 0;
    auto A32 = [&](size_t n) { float* p = wsf + foff; foff += n; return p; };
    float* h0f   = A32(BH);
    float* h1f   = A32(BH);
    float* extra0= A32(3 * HD);

    pack_w3<<<dim3(HD, 3), 256, 0, stream>>>(cw1, cw2, cw3, wp1, wp2, wp3);
    cvt_all<<<dim3(4096, 6), 256, 0, stream>>>(
        z, zb, (int)BH,
        w_ih, wihb, 3 * HD * (IND + HD),
        w_hh, whhb, (int)(3 * HH),
        h2xw, h2xbw, IND * HD,
        outw, outwb, OUTD * HD,
        d2ow, d2owb, OUTD * HD);
    ext0_k<<<3 * HD, 64, 0, stream>>>(w_ih, extra0);

    conv_gemm<1><<<dim3(8, 8, 3), 256, 0, stream>>>(1, zb, wp1, cb1,
        bn1g, bn1b, bn1m, bn1v, decab);
    conv_gemm<1><<<dim3(8, 8, 7), 256, 0, stream>>>(3, decab, wp2, cb2,
        bn2g, bn2b, bn2m, bn2v, decbb);
    conv_gemm<0><<<dim3(8, 8, 15), 256, 0, stream>>>(7, decbb, wp3, cb3,
        nullptr, nullptr, nullptr, nullptr, dec3b);

    // gdec[0..1] head (gdec[t>=2] come from gih(t-2) riders)
    gdec_head<<<384, 256, 0, stream>>>(dec3b, wihb, b_ih, gdecb);

    // ---- GRU chain with riders (out1 + gdec on gih; out0 on h2x) ----
    float* out0 = (float*)d_out;
    float* out1 = out0 + (size_t)TSTEPS * BATCH * OUTD;
    for (int t = 0; t < TSTEPS; ++t) {
        const u16* hbp   = t ? hsb + (size_t)(t - 1) * BH : zb;
        const float* hpf = (t == 0) ? z : (((t - 1) & 1) ? h1f : h0f);
        float* hwf = (t & 1) ? h1f : h0f;
        if (t > 0)   // 128 chain blocks + 512 riders (out0 rows of step t-1)
            h2x_k<<<640, 256, 0, stream>>>(t, hbp, h2xbw, h2xb, inpb,
                hsb, outwb, outb, out0);
        // 256 chain + (t<=12: 192 gdec[t+2] riders) + 512 out1 riders
        const int ggrid = (t <= 12) ? 960 : 768;
        gih_cell<<<ggrid, 256, 0, stream>>>(t,
            inpb, wihb, hbp, whhb, gdecb,
            t ? nullptr : extra0, b_hh, hpf, hwf, hsb + (size_t)t * BH,
            dec3b, d2owb, d2ob, out1, b_ih);
    }
    // tail: out0 rows of step 14
    proj_k<<<512, 256, 0, stream>>>(14 * 512, hsb, outwb, outb, out0);
}